// Round 2
// baseline (244.347 us; speedup 1.0000x reference)
//
#include <hip/hip_runtime.h>
#include <math.h>

// LightweightConv: B=16, T=4000, C=512, H=8, K=31, PAD=15, stride=1, dil=1.
// out[b,t,c] = sum_k softmax(w[c%H])[k] * x[b, t-15+k, c] + bias[c%H]
// Layout (B,T,C): contiguous in C -> lane = channel gives coalesced access;
// conv axis T has stride C. Memory-bound (262 MB / 2 GFLOP).

constexpr int NB   = 16;
constexpr int NT   = 4000;
constexpr int NC   = 512;
constexpr int NH   = 8;
constexpr int NK   = 31;
constexpr int CPAD = 15;

constexpr int SEG  = 80;            // time steps per thread (50 segments, exact)
constexpr int CH   = 16;            // chunk: outputs computed per inner iter
constexpr int HALO = NK - 1;        // 30
constexpr int WIN  = CH + HALO;     // 46-register rolling window

__global__ __launch_bounds__(512) void lconv_kernel(
    const float* __restrict__ x,
    const float* __restrict__ w,
    const float* __restrict__ bias,
    float* __restrict__ out)
{
    const int c  = threadIdx.x;          // 0..511, lane-contiguous -> coalesced
    const int b  = blockIdx.y;
    const int t0 = blockIdx.x * SEG;
    const int h  = c & (NH - 1);         // channel c -> head c % 8

    // --- per-thread softmax of this head's 31-tap kernel (one-time, cached) ---
    float wr[NK];
    #pragma unroll
    for (int k = 0; k < NK; ++k) wr[k] = w[h * NK + k];
    float m = wr[0];
    #pragma unroll
    for (int k = 1; k < NK; ++k) m = fmaxf(m, wr[k]);
    float s = 0.0f;
    #pragma unroll
    for (int k = 0; k < NK; ++k) { wr[k] = __expf(wr[k] - m); s += wr[k]; }
    const float inv = 1.0f / s;
    #pragma unroll
    for (int k = 0; k < NK; ++k) wr[k] *= inv;
    const float bv = bias[h];

    const float* xb = x   + (size_t)b * NT * NC + c;
    float*       ob = out + (size_t)b * NT * NC + c;

    // --- rolling window: win[i] = x[b, tc - PAD + i, c] for current chunk tc ---
    float win[WIN];

    // prologue: win[0..HALO-1] = x[t0-15 .. t0+14]  (t < NT always here)
    #pragma unroll
    for (int i = 0; i < HALO; ++i) {
        const int t = t0 - CPAD + i;
        win[i] = (t >= 0) ? xb[(size_t)t * NC] : 0.0f;
    }

    #pragma unroll 1
    for (int tc = t0; tc < t0 + SEG; tc += CH) {
        // load CH new inputs: win[HALO+j] = x[tc+15+j]  (t >= 0 always here)
        #pragma unroll
        for (int j = 0; j < CH; ++j) {
            const int t = tc + CPAD + j;
            win[HALO + j] = (t < NT) ? xb[(size_t)t * NC] : 0.0f;
        }
        // compute CH outputs: out[tc+j] = sum_k win[j+k] * wr[k] + bias
        #pragma unroll
        for (int j = 0; j < CH; ++j) {
            float acc = bv;
            #pragma unroll
            for (int k = 0; k < NK; ++k) acc = fmaf(win[j + k], wr[k], acc);
            ob[(size_t)(tc + j) * NC] = acc;
        }
        // shift window by CH (all static indices -> stays in VGPRs)
        #pragma unroll
        for (int i = 0; i < HALO; ++i) win[i] = win[i + CH];
    }
}

extern "C" void kernel_launch(void* const* d_in, const int* in_sizes, int n_in,
                              void* d_out, int out_size, void* d_ws, size_t ws_size,
                              hipStream_t stream) {
    const float* x    = (const float*)d_in[0];   // (B, T, C) f32
    const float* w    = (const float*)d_in[1];   // (H, 1, K) f32
    const float* bias = (const float*)d_in[2];   // (H,) f32
    float*       out  = (float*)d_out;           // (B, T, C) f32

    dim3 grid(NT / SEG, NB);                     // (50, 16) = 800 blocks
    lconv_kernel<<<grid, 512, 0, stream>>>(x, w, bias, out);
}

// Round 5
// 236.394 us; speedup vs baseline: 1.0336x; 1.0336x over previous
//
#include <hip/hip_runtime.h>
#include <math.h>

// LightweightConv: B=16, T=4000, C=512, H=8, K=31, PAD=15.
// out[b,t,c] = sum_k wn[c%8][k] * x[b, t-15+k, c] + bias[c%8],  wn = softmax(w)
// (B,T,C) contiguous in C -> lane = channel, coalesced 4B/lane.
// Memory-bound: 262 MB unique traffic -> ~42 us floor @ 6.3 TB/s.
// R2 diagnosis: latency-bound (2.4 TB/s, occ 31%, VGPR 44 = window not kept
// resident). Fix: single-shot threads (46 loads in flight), 8000 blocks,
// explicit 128-VGPR budget, softmax hoisted to a pre-kernel.

constexpr int NB   = 16;
constexpr int NT   = 4000;
constexpr int NC   = 512;
constexpr int NH   = 8;
constexpr int NK   = 31;
constexpr int CPAD = 15;

constexpr int CH   = 16;            // outputs per thread (250 t-chunks exact)
constexpr int HALO = NK - 1;        // 30
constexpr int WIN  = CH + HALO;     // 46 loads per thread

// --- pre-kernel: softmax-normalize the (8,31) weight table into d_ws ---
__global__ __launch_bounds__(64) void softmax_w_kernel(
    const float* __restrict__ w, float* __restrict__ wn)
{
    const int h = threadIdx.x;
    if (h >= NH) return;
    float v[NK];
    float m = -1e30f;
    #pragma unroll
    for (int k = 0; k < NK; ++k) { v[k] = w[h * NK + k]; m = fmaxf(m, v[k]); }
    float s = 0.0f;
    #pragma unroll
    for (int k = 0; k < NK; ++k) { v[k] = __expf(v[k] - m); s += v[k]; }
    const float inv = 1.0f / s;
    #pragma unroll
    for (int k = 0; k < NK; ++k) wn[h * NK + k] = v[k] * inv;
}

// --- main kernel: one thread = one (b, c, 16-output t-chunk) ---
__global__ __launch_bounds__(256, 4) void lconv_kernel(
    const float* __restrict__ x,
    const float* __restrict__ wn,
    const float* __restrict__ bias,
    float* __restrict__ out)
{
    const int c  = blockIdx.y * 256 + threadIdx.x;   // channel, lane-contiguous
    const int b  = blockIdx.z;
    const int t0 = blockIdx.x * CH;
    const int h  = c & (NH - 1);

    const float* xb = x   + (size_t)b * NT * NC + c;
    float*       ob = out + (size_t)b * NT * NC + c;

    // normalized weights for this head (L1-broadcast, 992 B table)
    float wr[NK];
    #pragma unroll
    for (int k = 0; k < NK; ++k) wr[k] = wn[h * NK + k];
    const float bv = bias[h];

    // full window: win[i] = x[b, t0-15+i, c], i in [0,46) -- all loads
    // independent, issue back-to-back for max MLP
    float win[WIN];
    if (t0 >= CPAD && t0 + CH - 1 + CPAD < NT) {
        // interior chunk (248 of 250): no predication at all
        #pragma unroll
        for (int i = 0; i < WIN; ++i)
            win[i] = xb[(size_t)(t0 - CPAD + i) * NC];
    } else {
        #pragma unroll
        for (int i = 0; i < WIN; ++i) {
            const int t = t0 - CPAD + i;
            win[i] = (t >= 0 && t < NT) ? xb[(size_t)t * NC] : 0.0f;
        }
    }

    // 16 outputs, fully unrolled, static indices only
    #pragma unroll
    for (int j = 0; j < CH; ++j) {
        float acc = bv;
        #pragma unroll
        for (int k = 0; k < NK; ++k) acc = fmaf(win[j + k], wr[k], acc);
        ob[(size_t)(t0 + j) * NC] = acc;
    }
}

extern "C" void kernel_launch(void* const* d_in, const int* in_sizes, int n_in,
                              void* d_out, int out_size, void* d_ws, size_t ws_size,
                              hipStream_t stream) {
    const float* x    = (const float*)d_in[0];   // (B, T, C) f32
    const float* w    = (const float*)d_in[1];   // (H, 1, K) f32
    const float* bias = (const float*)d_in[2];   // (H,) f32
    float*       out  = (float*)d_out;           // (B, T, C) f32
    float*       wnrm = (float*)d_ws;            // 8*31 f32 normalized weights

    softmax_w_kernel<<<1, 64, 0, stream>>>(w, wnrm);
    dim3 grid(NT / CH, NC / 256, NB);            // (250, 2, 16) = 8000 blocks
    lconv_kernel<<<grid, 256, 0, stream>>>(x, wnrm, bias, out);
}